// Round 2
// baseline (219.241 us; speedup 1.0000x reference)
//
#include <hip/hip_runtime.h>

// out[2i]   = x[2i]
// out[2i+1] = x[2i+1] - x[2i] / 50
// Pure elementwise on adjacent pairs -> memory-bound. Vectorize as float4
// (two pairs per thread), coalesced 16B/lane.
//
// Round-1 lesson: sizing from in_sizes[0] caused 4x OOB writes (clobbered the
// harness's pristine input copy -> post-timing divergence). out_size is the
// verified fp32 element count (harness validates exactly out_size floats), so
// all indexing derives from out_size only.

__global__ __launch_bounds__(256) void dn_kernel(const float4* __restrict__ in,
                                                 float4* __restrict__ out,
                                                 int n4) {
    int i = blockIdx.x * blockDim.x + threadIdx.x;
    if (i < n4) {
        float4 v = in[i];
        float4 r;
        r.x = v.x;
        r.y = v.y - v.x * (1.0f / 50.0f);
        r.z = v.z;
        r.w = v.w - v.z * (1.0f / 50.0f);
        out[i] = r;
    }
}

// Scalar tail in case out_size is not a multiple of 4 (not expected here,
// but keeps the kernel fully general without relying on in_sizes).
__global__ void dn_tail_kernel(const float* __restrict__ in,
                               float* __restrict__ out,
                               int start, int n) {
    int i = start + blockIdx.x * blockDim.x + threadIdx.x;
    if (i < n) {
        float v = in[i];
        if (i & 1) {
            out[i] = v - in[i - 1] * (1.0f / 50.0f);
        } else {
            out[i] = v;
        }
    }
}

extern "C" void kernel_launch(void* const* d_in, const int* in_sizes, int n_in,
                              void* d_out, int out_size, void* d_ws, size_t ws_size,
                              hipStream_t stream) {
    const float* in = (const float*)d_in[0];
    float* out = (float*)d_out;
    int n = out_size;             // 128*64*64*64 = 33,554,432 fp32 elements
    int n4 = n / 4;               // float4 count: 8,388,608
    if (n4 > 0) {
        int block = 256;
        int grid = (n4 + block - 1) / block;
        dn_kernel<<<grid, block, 0, stream>>>((const float4*)in, (float4*)out, n4);
    }
    int tail_start = n4 * 4;
    int tail = n - tail_start;
    if (tail > 0) {
        dn_tail_kernel<<<1, 64, 0, stream>>>(in, out, tail_start, n);
    }
}